// Round 6
// baseline (418.894 us; speedup 1.0000x reference)
//
#include <hip/hip_runtime.h>
#include <hip/hip_cooperative_groups.h>

namespace cg = cooperative_groups;

#define N_ATOMS 5000
#define N_EDGES 40000
#define N_TRIP  250000
#define NH      4
#define NHID    64
#define NOUT    64
#define NTYPES  108
#define NPAIRS  (NTYPES * NTYPES)
#define EPSV    0.001f
#define PI_F    3.14159265358979323846f

#define CAPT    48      // max triplets/edge (lambda=6.25; P(overflow) ~ 1e-24)
#define CAPE    64      // max edges/atom   (lambda=8;    P(overflow) ~ 1e-80)
#define GRID    1024    // 4 blocks/CU x 256 CUs -> co-resident for cooperative launch
#define BLK     256
#define GSZ     (GRID * BLK)

struct Params {
    const float* r; const float* dnr; const float* key_emb; const float* value_emb;
    const float* a_p; const float* b_p; const float* c_p; const float* d_p;
    const int* src_idx; const int* dst_idx; const int* lg_src; const int* lg_dst;
    const int* atomic_number;
    float* out;
    int* histT; int* histE; int* za_e; int* zb_e;
    float* W; float4* edge_val; float4* bucketT; int* bucketE;
};

// ---- Phase 0: zero hists, per-edge types, 108x108 per-head key-dot table ----
__device__ __forceinline__ void prep_phase(const Params& p, int tid) {
    for (int i = tid; i < N_EDGES; i += GSZ) {
        p.za_e[i] = p.atomic_number[p.src_idx[i]];
        p.zb_e[i] = p.atomic_number[p.dst_idx[i]];
        p.histT[i] = 0;
    }
    for (int i = tid; i < N_ATOMS; i += GSZ) p.histE[i] = 0;
    for (int i = tid; i < NPAIRS; i += GSZ) {
        int za = i / NTYPES, zb = i - za * NTYPES;
        const float* ra = p.key_emb + za * (NHID * NH);
        const float* rb = p.key_emb + zb * (NHID * NH);
        float acc0 = 0.f, acc1 = 0.f, acc2 = 0.f, acc3 = 0.f;
        #pragma unroll 8
        for (int k = 0; k < NHID; ++k) {
            float4 va = *reinterpret_cast<const float4*>(ra + k * NH);
            float4 vb = *reinterpret_cast<const float4*>(rb + k * NH);
            acc0 += va.x * vb.x;
            acc1 += va.y * vb.y;
            acc2 += va.z * vb.z;
            acc3 += va.w * vb.w;
        }
        float* wp = p.W + i * NH;
        wp[0] = acc0; wp[1] = acc1; wp[2] = acc2; wp[3] = acc3;
    }
}

// ---- Phase 1: per-triplet value -> bucket slot (rank = atomic return) ----
__device__ __forceinline__ void trip_phase(const Params& p, int tid) {
    float A[NH], PHI[NH], C[NH], D[NH];
    #pragma unroll
    for (int h = 0; h < NH; ++h) {
        A[h]   = p.a_p[h];
        PHI[h] = A[h] * (PI_F * 0.5f) + fmodf(p.b_p[h], PI_F);
        C[h]   = p.c_p[h];
        D[h]   = p.d_p[h];
    }
    for (int t = tid; t < N_TRIP; t += GSZ) {
        int e1 = p.lg_src[t];
        int e2 = p.lg_dst[t];
        float ax = p.r[e1 * 3 + 0], ay = p.r[e1 * 3 + 1], az = p.r[e1 * 3 + 2];
        float bx = p.r[e2 * 3 + 0], by = p.r[e2 * 3 + 1], bz = p.r[e2 * 3 + 2];
        // r1=-r[e1], r2=r[e2] -> cos = -(a.b)/(|a||b|)
        float dot = -(ax * bx + ay * by + az * bz);
        float nn  = (ax * ax + ay * ay + az * az) * (bx * bx + by * by + bz * bz);
        float c   = dot * rsqrtf(nn);
        c = fminf(fmaxf(c, -1.0f), 1.0f);
        c = fminf(fmaxf(c, -EPSV), EPSV);
        // theta = acos(c) = pi/2 - asin(c) = pi/2 - c (+O(c^3)=1.7e-10, below fp32 ulp)
        float dn  = p.dnr[t];
        float dn2 = dn * dn;
        const float* wp = p.W + (p.za_e[e1] * NTYPES + p.zb_e[e2]) * NH;
        float v[NH];
        #pragma unroll
        for (int h = 0; h < NH; ++h) {
            float u    = PHI[h] - A[h] * c;               // A*theta + B
            float base = (__cosf(u) + 1.0f) * 0.5f;       // in [0,1]
            float ang  = __powf(base, C[h]);
            float rad  = __expf(-D[h] * dn2);
            v[h] = wp[h] * ang * rad;
        }
        int pos = atomicAdd(&p.histT[e1], 1);
        if (pos < CAPT)
            p.bucketT[e1 * CAPT + pos] = make_float4(v[0], v[1], v[2], v[3]);
    }
}

// ---- Phase 2: per-edge mean over its triplet bucket + scatter into atom bucket ----
__device__ __forceinline__ void edge_phase(const Params& p, int tid) {
    for (int e = tid; e < N_EDGES; e += GSZ) {
        int cnt = p.histT[e];
        int m   = cnt < CAPT ? cnt : CAPT;
        const float4* b = p.bucketT + e * CAPT;
        float sx = 0.f, sy = 0.f, sz = 0.f, sw = 0.f;
        for (int q = 0; q < m; ++q) {
            float4 v = b[q];
            sx += v.x; sy += v.y; sz += v.z; sw += v.w;
        }
        float inv = 1.0f / (float)(cnt > 1 ? cnt : 1);
        p.edge_val[e] = make_float4(sx * inv, sy * inv, sz * inv, sw * inv);
        int n = p.src_idx[e];
        int pos = atomicAdd(&p.histE[n], 1);
        if (pos < CAPE)
            p.bucketE[n * CAPE + pos] = e;
    }
}

// ---- Phase 3: per (atom, out) gather; wave = one atom, lane = o (coalesced) ----
__device__ __forceinline__ void atom_phase(const Params& p, int tid) {
    for (int id = tid; id < N_ATOMS * NOUT; id += GSZ) {
        int n = id >> 6;
        int o = id & 63;
        int cnt = p.histE[n];
        int m   = cnt < CAPE ? cnt : CAPE;
        const int* be = p.bucketE + n * CAPE;
        float acc = 0.f;
        for (int q = 0; q < m; ++q) {
            int e = be[q];
            float4 mv = p.edge_val[e];
            float4 v  = *reinterpret_cast<const float4*>(
                            p.value_emb + p.zb_e[e] * (NOUT * NH) + o * NH);
            acc += v.x * mv.x + v.y * mv.y + v.z * mv.z + v.w * mv.w;
        }
        p.out[id] = acc / (float)(cnt > 1 ? cnt : 1);
    }
}

__global__ __launch_bounds__(BLK, 4) void fused_kernel(Params p) {
    cg::grid_group g = cg::this_grid();
    int tid = blockIdx.x * BLK + threadIdx.x;
    prep_phase(p, tid);
    g.sync();
    trip_phase(p, tid);
    g.sync();
    edge_phase(p, tid);
    g.sync();
    atom_phase(p, tid);
}

// Fallback path (regular launches) in case cooperative launch is rejected.
__global__ __launch_bounds__(BLK, 4) void prep_k(Params p) { prep_phase(p, blockIdx.x * BLK + threadIdx.x); }
__global__ __launch_bounds__(BLK, 4) void trip_k(Params p) { trip_phase(p, blockIdx.x * BLK + threadIdx.x); }
__global__ __launch_bounds__(BLK, 4) void edge_k(Params p) { edge_phase(p, blockIdx.x * BLK + threadIdx.x); }
__global__ __launch_bounds__(BLK, 4) void atom_k(Params p) { atom_phase(p, blockIdx.x * BLK + threadIdx.x); }

extern "C" void kernel_launch(void* const* d_in, const int* in_sizes, int n_in,
                              void* d_out, int out_size, void* d_ws, size_t ws_size,
                              hipStream_t stream) {
    char* ws = (char*)d_ws;
    size_t off = 0;
    auto take = [&](size_t bytes) -> char* {
        char* ptr = ws + off;
        off = (off + bytes + 255) & ~(size_t)255;
        return ptr;
    };

    Params p;
    p.r             = (const float*)d_in[0];
    p.dnr           = (const float*)d_in[1];
    p.key_emb       = (const float*)d_in[2];
    p.value_emb     = (const float*)d_in[3];
    p.a_p           = (const float*)d_in[4];
    p.b_p           = (const float*)d_in[5];
    p.c_p           = (const float*)d_in[6];
    p.d_p           = (const float*)d_in[7];
    p.src_idx       = (const int*)d_in[8];
    p.dst_idx       = (const int*)d_in[9];
    p.lg_src        = (const int*)d_in[10];
    p.lg_dst        = (const int*)d_in[11];
    p.atomic_number = (const int*)d_in[12];
    p.out           = (float*)d_out;

    p.histT    = (int*)   take(N_EDGES * sizeof(int));
    p.histE    = (int*)   take(N_ATOMS * sizeof(int));
    p.za_e     = (int*)   take(N_EDGES * sizeof(int));
    p.zb_e     = (int*)   take(N_EDGES * sizeof(int));
    p.W        = (float*) take(NPAIRS * NH * sizeof(float));
    p.edge_val = (float4*)take(N_EDGES * sizeof(float4));
    p.bucketT  = (float4*)take((size_t)N_EDGES * CAPT * sizeof(float4));  // ~30.7 MB
    p.bucketE  = (int*)   take((size_t)N_ATOMS * CAPE * sizeof(int));     // ~1.3 MB

    void* args[] = { &p };
    hipError_t err = hipLaunchCooperativeKernel((const void*)fused_kernel,
                                                dim3(GRID), dim3(BLK),
                                                args, 0, stream);
    if (err != hipSuccess) {
        // cooperative launch unavailable: same phases as regular kernels
        prep_k<<<GRID, BLK, 0, stream>>>(p);
        trip_k<<<GRID, BLK, 0, stream>>>(p);
        edge_k<<<GRID, BLK, 0, stream>>>(p);
        atom_k<<<GRID, BLK, 0, stream>>>(p);
    }
}

// Round 7
// 54.085 us; speedup vs baseline: 7.7451x; 7.7451x over previous
//
#include <hip/hip_runtime.h>

#define N_ATOMS 5000
#define N_EDGES 40000
#define N_TRIP  250000
#define NH      4
#define NHID    64
#define NOUT    64
#define NTYPES  108
#define NPAIRS  (NTYPES * NTYPES)
#define EPSV    0.001f
#define PI_F    3.14159265358979323846f

#define CAPT    48      // max triplets/edge (lambda=6.25; P(overflow) ~ 1e-24 on fixed data)
#define CAPE    64      // max edges/atom   (lambda=8;    P(overflow) ~ 1e-80)

// ---------------------------------------------------------------------------
// K1: zero hists + per-edge types + 108x108 per-head key dot-product table
// ---------------------------------------------------------------------------
__global__ void prep_kernel(const float* __restrict__ key_emb,
                            const int* __restrict__ src_idx,
                            const int* __restrict__ dst_idx,
                            const int* __restrict__ atomic_number,
                            float* __restrict__ W,
                            int* __restrict__ za_e,
                            int* __restrict__ zb_e,
                            int* __restrict__ histT,
                            int* __restrict__ histE) {
    int tid = blockIdx.x * blockDim.x + threadIdx.x;
    if (tid < N_EDGES) {
        za_e[tid] = atomic_number[src_idx[tid]];
        zb_e[tid] = atomic_number[dst_idx[tid]];
        histT[tid] = 0;
    }
    if (tid < N_ATOMS) histE[tid] = 0;
    if (tid < NPAIRS) {
        int za = tid / NTYPES, zb = tid - za * NTYPES;
        const float* ra = key_emb + za * (NHID * NH);
        const float* rb = key_emb + zb * (NHID * NH);
        float acc0 = 0.f, acc1 = 0.f, acc2 = 0.f, acc3 = 0.f;
        #pragma unroll 8
        for (int k = 0; k < NHID; ++k) {
            float4 va = *reinterpret_cast<const float4*>(ra + k * NH);
            float4 vb = *reinterpret_cast<const float4*>(rb + k * NH);
            acc0 += va.x * vb.x;
            acc1 += va.y * vb.y;
            acc2 += va.z * vb.z;
            acc3 += va.w * vb.w;
        }
        float* wp = W + tid * NH;
        wp[0] = acc0; wp[1] = acc1; wp[2] = acc2; wp[3] = acc3;
    }
}

// ---------------------------------------------------------------------------
// K2: per-triplet value -> bucket slot (slot index = atomicAdd return)
//     hist + rank + geometry + value write, all fused; no scan needed.
// ---------------------------------------------------------------------------
__global__ void trip_kernel(const float* __restrict__ r,
                            const float* __restrict__ dnr,
                            const float* __restrict__ a_p,
                            const float* __restrict__ b_p,
                            const float* __restrict__ c_p,
                            const float* __restrict__ d_p,
                            const int* __restrict__ lg_src,
                            const int* __restrict__ lg_dst,
                            const int* __restrict__ za_e,
                            const int* __restrict__ zb_e,
                            const float* __restrict__ W,
                            int* __restrict__ histT,
                            float4* __restrict__ bucketT) {
    int t = blockIdx.x * blockDim.x + threadIdx.x;
    if (t >= N_TRIP) return;

    int e1 = lg_src[t];
    int e2 = lg_dst[t];

    float ax = r[e1 * 3 + 0], ay = r[e1 * 3 + 1], az = r[e1 * 3 + 2];
    float bx = r[e2 * 3 + 0], by = r[e2 * 3 + 1], bz = r[e2 * 3 + 2];

    // r1=-r[e1], r2=r[e2] -> cos = -(a.b)/(|a||b|)
    float dot = -(ax * bx + ay * by + az * bz);
    float nn  = (ax * ax + ay * ay + az * az) * (bx * bx + by * by + bz * bz);
    float c   = dot * rsqrtf(nn);
    c = fminf(fmaxf(c, -1.0f), 1.0f);
    c = fminf(fmaxf(c, -EPSV), EPSV);
    // theta = acos(c) = pi/2 - asin(c) = pi/2 - c  (|c|<=1e-3: error 1.7e-10 < fp32 ulp)

    float dn  = dnr[t];
    float dn2 = dn * dn;

    const float* wp = W + (za_e[e1] * NTYPES + zb_e[e2]) * NH;

    float v[NH];
    #pragma unroll
    for (int h = 0; h < NH; ++h) {
        float A   = a_p[h];
        float u   = (A * (PI_F * 0.5f) + fmodf(b_p[h], PI_F)) - A * c;  // A*theta + B
        float base = (__cosf(u) + 1.0f) * 0.5f;        // in [0,1]
        float ang  = __powf(base, c_p[h]);
        float rad  = __expf(-d_p[h] * dn2);
        v[h] = wp[h] * ang * rad;
    }

    int pos = atomicAdd(&histT[e1], 1);
    if (pos < CAPT)
        bucketT[e1 * CAPT + pos] = make_float4(v[0], v[1], v[2], v[3]);
}

// ---------------------------------------------------------------------------
// K3: per-edge mean over its triplet bucket + scatter edge id into atom bucket
// ---------------------------------------------------------------------------
__global__ void edge_kernel(const int* __restrict__ src_idx,
                            const int* __restrict__ histT,
                            const float4* __restrict__ bucketT,
                            int* __restrict__ histE,
                            int* __restrict__ bucketE,
                            float4* __restrict__ edge_val) {
    int e = blockIdx.x * blockDim.x + threadIdx.x;
    if (e >= N_EDGES) return;

    int cnt = histT[e];
    int m   = cnt < CAPT ? cnt : CAPT;
    const float4* b = bucketT + e * CAPT;
    float sx = 0.f, sy = 0.f, sz = 0.f, sw = 0.f;
    for (int q = 0; q < m; ++q) {
        float4 v = b[q];
        sx += v.x; sy += v.y; sz += v.z; sw += v.w;
    }
    float inv = 1.0f / (float)(cnt > 1 ? cnt : 1);
    edge_val[e] = make_float4(sx * inv, sy * inv, sz * inv, sw * inv);

    int n = src_idx[e];
    int pos = atomicAdd(&histE[n], 1);
    if (pos < CAPE)
        bucketE[n * CAPE + pos] = e;
}

// ---------------------------------------------------------------------------
// K4: per (atom, out): gather atom's edges, dot value_emb rows, mean, store
// ---------------------------------------------------------------------------
__global__ void atom_kernel(const float* __restrict__ value_emb,
                            const int* __restrict__ zb_e,
                            const int* __restrict__ histE,
                            const int* __restrict__ bucketE,
                            const float4* __restrict__ edge_val,
                            float* __restrict__ out) {
    int id = blockIdx.x * blockDim.x + threadIdx.x;
    if (id >= N_ATOMS * NOUT) return;
    int n = id >> 6;
    int o = id & 63;

    int cnt = histE[n];
    int m   = cnt < CAPE ? cnt : CAPE;
    const int* be = bucketE + n * CAPE;
    float acc = 0.f;
    for (int q = 0; q < m; ++q) {
        int e = be[q];
        float4 mv = edge_val[e];
        float4 v  = *reinterpret_cast<const float4*>(
                        value_emb + zb_e[e] * (NOUT * NH) + o * NH);
        acc += v.x * mv.x + v.y * mv.y + v.z * mv.z + v.w * mv.w;
    }
    out[id] = acc / (float)(cnt > 1 ? cnt : 1);
}

extern "C" void kernel_launch(void* const* d_in, const int* in_sizes, int n_in,
                              void* d_out, int out_size, void* d_ws, size_t ws_size,
                              hipStream_t stream) {
    const float* r         = (const float*)d_in[0];
    const float* dnr       = (const float*)d_in[1];
    const float* key_emb   = (const float*)d_in[2];
    const float* value_emb = (const float*)d_in[3];
    const float* a_p       = (const float*)d_in[4];
    const float* b_p       = (const float*)d_in[5];
    const float* c_p       = (const float*)d_in[6];
    const float* d_p       = (const float*)d_in[7];
    const int* src_idx   = (const int*)d_in[8];
    const int* dst_idx   = (const int*)d_in[9];
    const int* lg_src    = (const int*)d_in[10];
    const int* lg_dst    = (const int*)d_in[11];
    const int* atomic_number = (const int*)d_in[12];
    float* out = (float*)d_out;

    char* ws = (char*)d_ws;
    size_t off = 0;
    auto take = [&](size_t bytes) -> char* {
        char* ptr = ws + off;
        off = (off + bytes + 255) & ~(size_t)255;
        return ptr;
    };
    int*    histT    = (int*)   take(N_EDGES * sizeof(int));
    int*    histE    = (int*)   take(N_ATOMS * sizeof(int));
    int*    za_e     = (int*)   take(N_EDGES * sizeof(int));
    int*    zb_e     = (int*)   take(N_EDGES * sizeof(int));
    float*  W        = (float*) take(NPAIRS * NH * sizeof(float));
    float4* edge_val = (float4*)take(N_EDGES * sizeof(float4));
    float4* bucketT  = (float4*)take((size_t)N_EDGES * CAPT * sizeof(float4)); // ~30.7 MB
    int*    bucketE  = (int*)   take((size_t)N_ATOMS * CAPE * sizeof(int));    // ~1.3 MB

    {   // K1: grid covers N_EDGES (> NPAIRS, > N_ATOMS)
        int n = (N_EDGES > NPAIRS ? N_EDGES : NPAIRS);
        prep_kernel<<<(n + 255) / 256, 256, 0, stream>>>(
            key_emb, src_idx, dst_idx, atomic_number, W, za_e, zb_e, histT, histE);
    }
    trip_kernel<<<(N_TRIP + 255) / 256, 256, 0, stream>>>(
        r, dnr, a_p, b_p, c_p, d_p, lg_src, lg_dst, za_e, zb_e, W, histT, bucketT);
    edge_kernel<<<(N_EDGES + 255) / 256, 256, 0, stream>>>(
        src_idx, histT, bucketT, histE, bucketE, edge_val);
    atom_kernel<<<(N_ATOMS * NOUT + 255) / 256, 256, 0, stream>>>(
        value_emb, zb_e, histE, bucketE, edge_val, out);
}